// Round 1
// baseline (986.418 us; speedup 1.0000x reference)
//
#include <hip/hip_runtime.h>
#include <math.h>

// DeformableAttention2D — fp32 reference-accurate implementation.
// Sizes (fixed): B=4, N=256, DIM=256, HEADS=8, GROUPS=8, INNER=512, DH=64,
// cross-attn head dim 32, rgb 4x4 (16 tokens), CPB MLP 2->64->64->1.
// ws layout (floats): kx[16384] vx[16384] qT[524288] kT[524288] vT[524288]
//                     vgrid[16384] aoT[524288]  => ~8.6 MB total.

#define DIMC 256
#define NQ 256
#define HEADS 8
#define GROUPS 8
#define INNER 512
#define DH 64      // deformable head dim
#define HDX 32     // cross-attn head dim
#define HWT 16     // rgb tokens (4*4)

__device__ __forceinline__ float gelu_exact(float x) {
    return 0.5f * x * (1.f + erff(x * 0.70710678118654752f));
}

__device__ __forceinline__ float samp4(const float* __restrict__ img, int yi, int xi) {
    bool valid = (xi >= 0) && (xi < 4) && (yi >= 0) && (yi < 4);
    int idx = min(max(yi, 0), 3) * 4 + min(max(xi, 0), 3);
    return valid ? img[idx] : 0.f;
}

// ---------------- K1: kx, vx  [b,16,256] ----------------
__global__ __launch_bounds__(256) void k1_kv(const float* __restrict__ rgb,
        const float* __restrict__ in_w, const float* __restrict__ in_b,
        float* __restrict__ kx, float* __restrict__ vx) {
    int b = blockIdx.x >> 4;
    int t = blockIdx.x & 15;
    int c = threadIdx.x;
    __shared__ float kvin[DIMC];
    // sinusoid table: ang = pos / 10000^((c>>1)/128); even c -> sin, odd -> cos
    float ang = (float)t * powf(10000.f, -(float)(c >> 1) * (1.f / 128.f));
    float sv = (c & 1) ? cosf(ang) : sinf(ang);
    kvin[c] = rgb[(b * DIMC + c) * HWT + t] + sv;
    __syncthreads();
    float ak = in_b[DIMC + c], av = in_b[2 * DIMC + c];
    const float* wk = in_w + (DIMC + c) * DIMC;
    const float* wv = in_w + (2 * DIMC + c) * DIMC;
    for (int d = 0; d < DIMC; ++d) {
        float x = kvin[d];
        ak = fmaf(wk[d], x, ak);
        av = fmaf(wv[d], x, av);
    }
    kx[(b * HWT + t) * DIMC + c] = ak;
    vx[(b * HWT + t) * DIMC + c] = av;
}

// ---------------- K2: per (b,n): cross-attn + q/offsets/sample + k/v ----------------
__global__ __launch_bounds__(256) void k2_qkv(
        const float* __restrict__ pose_feat, const float* __restrict__ rgb,
        const float* __restrict__ pose_init, const float* __restrict__ in_w,
        const float* __restrict__ in_b, const float* __restrict__ mow,
        const float* __restrict__ mob, const float* __restrict__ pe_gauss,
        const float* __restrict__ off_w1, const float* __restrict__ off_b1,
        const float* __restrict__ off_w2,
        const float* __restrict__ q_w, const float* __restrict__ k_w,
        const float* __restrict__ v_w,
        const float* __restrict__ kx, const float* __restrict__ vx,
        float* __restrict__ qT, float* __restrict__ kT, float* __restrict__ vT,
        float* __restrict__ vgrid_g) {
    int b = blockIdx.x >> 8, n = blockIdx.x & 255;
    int t = threadIdx.x;
    __shared__ float xs[DIMC], qxs[DIMC], lg[128], psm[128], ctx[DIMC], x2[DIMC];
    __shared__ float qls[INNER], kvs[DIMC];
    __shared__ float vgls[GROUPS][2];

    float p0 = pose_init[(b * 2 + 0) * NQ + n];
    float p1 = pose_init[(b * 2 + 1) * NQ + n];
    float g0 = 2.f * p0 - 1.f, g1 = 2.f * p1 - 1.f;

    // point embedding + pose_feat column
    float pfv = pose_feat[(b * DIMC + t) * NQ + n];
    {
        int j = t & 127;
        float cc = (g0 * pe_gauss[j] + g1 * pe_gauss[128 + j]) * 6.28318530717958648f;
        xs[t] = pfv + ((t < 128) ? sinf(cc) : cosf(cc));
    }
    __syncthreads();
    // qx = xs @ Wq^T + bq
    {
        float a = in_b[t];
        const float* w = in_w + t * DIMC;
        for (int d = 0; d < DIMC; ++d) a = fmaf(w[d], xs[d], a);
        qxs[t] = a;
    }
    __syncthreads();
    // cross-attn logits (8 heads x 16 tokens)
    if (t < 128) {
        int h = t >> 4, tt = t & 15;
        const float* kp = kx + (b * HWT + tt) * DIMC + h * HDX;
        float a = 0.f;
        #pragma unroll
        for (int d = 0; d < HDX; ++d) a = fmaf(qxs[h * HDX + d], kp[d], a);
        lg[t] = a * 0.17677669529663689f;  // 1/sqrt(32)
    }
    __syncthreads();
    if (t < 8) {
        float m = -1e30f;
        for (int tt = 0; tt < 16; ++tt) m = fmaxf(m, lg[t * 16 + tt]);
        float s = 0.f;
        for (int tt = 0; tt < 16; ++tt) { float e = expf(lg[t * 16 + tt] - m); psm[t * 16 + tt] = e; s += e; }
        float r = 1.f / s;
        for (int tt = 0; tt < 16; ++tt) psm[t * 16 + tt] *= r;
    }
    __syncthreads();
    // ctx = attn @ vx
    {
        int h = t >> 5;
        float a = 0.f;
        const float* vp = vx + b * HWT * DIMC + t;
        #pragma unroll
        for (int tt = 0; tt < 16; ++tt) a = fmaf(psm[h * 16 + tt], vp[tt * DIMC], a);
        ctx[t] = a;
    }
    __syncthreads();
    // pose_cross + residual
    {
        float a = mob[t];
        const float* w = mow + t * DIMC;
        for (int d = 0; d < DIMC; ++d) a = fmaf(w[d], ctx[d], a);
        x2[t] = pfv + a;
    }
    __syncthreads();
    // grouped q conv (8 groups: 32 -> 64)
    #pragma unroll
    for (int rep = 0; rep < 2; ++rep) {
        int ch = t + rep * 256;
        int g = ch >> 6;
        const float* w = q_w + ch * 32;
        const float* xp = x2 + g * 32;
        float a = 0.f;
        #pragma unroll
        for (int ci = 0; ci < 32; ++ci) a = fmaf(w[ci], xp[ci], a);
        qls[ch] = a;
        qT[(b * NQ + n) * INNER + ch] = a;
    }
    __syncthreads();
    // offsets per group, vgrid
    {
        int g = t >> 5, l = t & 31;
        float s0 = 0.f, s1 = 0.f;
        #pragma unroll
        for (int jh = 0; jh < 2; ++jh) {
            int jj = l + 32 * jh;
            float e = gelu_exact(fmaf(qls[g * 64 + jj], off_w1[jj], off_b1[jj]));
            s0 = fmaf(e, off_w2[jj], s0);
            s1 = fmaf(e, off_w2[64 + jj], s1);
        }
        #pragma unroll
        for (int o = 16; o > 0; o >>= 1) {
            s0 += __shfl_xor(s0, o, 32);
            s1 += __shfl_xor(s1, o, 32);
        }
        if (l == 0) {
            float vgx = g0 + tanhf(s0) * (2.f / 3.f);
            float vgy = g1 + tanhf(s1) * (2.f / 3.f);
            vgls[g][0] = vgx; vgls[g][1] = vgy;
            float* vp = vgrid_g + ((b * GROUPS + g) * NQ + n) * 2;
            vp[0] = vgx; vp[1] = vgy;
        }
    }
    __syncthreads();
    // bilinear grid sample (zero padding, align_corners=False)
    {
        int g = t >> 5, c = t & 31;
        float x = (vgls[g][0] + 1.f) * 2.f - 0.5f;
        float y = (vgls[g][1] + 1.f) * 2.f - 0.5f;
        float x0f = floorf(x), y0f = floorf(y);
        float wx = x - x0f, wy = y - y0f;
        int x0 = (int)x0f, y0 = (int)y0f;
        const float* img = rgb + (b * DIMC + g * 32 + c) * HWT;
        float v00 = samp4(img, y0, x0), v01 = samp4(img, y0, x0 + 1);
        float v10 = samp4(img, y0 + 1, x0), v11 = samp4(img, y0 + 1, x0 + 1);
        kvs[t] = v00 * (1.f - wx) * (1.f - wy) + v01 * wx * (1.f - wy)
               + v10 * (1.f - wx) * wy + v11 * wx * wy;
    }
    __syncthreads();
    // grouped k, v convs
    #pragma unroll
    for (int rep = 0; rep < 2; ++rep) {
        int ch = t + rep * 256;
        int g = ch >> 6;
        const float* xp = kvs + g * 32;
        const float* wkp = k_w + ch * 32;
        const float* wvp = v_w + ch * 32;
        float ak = 0.f, av = 0.f;
        #pragma unroll
        for (int ci = 0; ci < 32; ++ci) {
            float x = xp[ci];
            ak = fmaf(wkp[ci], x, ak);
            av = fmaf(wvp[ci], x, av);
        }
        kT[(b * NQ + n) * INNER + ch] = ak;
        vT[(b * NQ + n) * INNER + ch] = av;
    }
}

// ---------------- K3: sim + CPB bias MLP + softmax + attn@V ----------------
__global__ __launch_bounds__(256) void k3_attn(
        const float* __restrict__ pose_init, const float* __restrict__ vgrid_g,
        const float* __restrict__ qT, const float* __restrict__ kT,
        const float* __restrict__ vT,
        const float* __restrict__ w0, const float* __restrict__ b0,
        const float* __restrict__ w1, const float* __restrict__ b1,
        const float* __restrict__ w2, const float* __restrict__ b2,
        float* __restrict__ aoT) {
    int bg = blockIdx.x >> 5;        // 0..31
    int itile = blockIdx.x & 31;     // 0..31
    int b = bg >> 3, h = bg & 7;
    int i0 = itile * 8;
    int tid = threadIdx.x;
    int il = tid >> 5, lane = tid & 31;

    __shared__ __align__(16) float q_s[8][64];
    __shared__ float gi_s[8][2];
    __shared__ float vg_s[NQ][2];
    __shared__ float attn_s[8][NQ];
    __shared__ float ssum_s[8];

    for (int idx = tid; idx < 8 * 64; idx += 256) {
        int i = idx >> 6, d = idx & 63;
        q_s[i][d] = qT[(b * NQ + i0 + i) * INNER + h * 64 + d] * 0.125f;  // 64^-0.5
    }
    if (tid < 16) {
        int i = tid >> 1, comp = tid & 1;
        gi_s[i][comp] = 2.f * pose_init[(b * 2 + comp) * NQ + i0 + i] - 1.f;
    }
    for (int idx = tid; idx < NQ * 2; idx += 256) {
        vg_s[idx >> 1][idx & 1] = vgrid_g[bg * NQ * 2 + idx];
    }
    __syncthreads();

    float gx = gi_s[il][0], gy = gi_s[il][1];
    const int iglob = i0 + il;

    #pragma unroll 1
    for (int jj = 0; jj < 8; ++jj) {
        int j = jj * 32 + lane;
        // sim = (q*scale) . k
        float sim = 0.f;
        const float4* kp = (const float4*)(kT + (b * NQ + j) * INNER + h * 64);
        const float4* qp = (const float4*)(&q_s[il][0]);
        #pragma unroll
        for (int d4 = 0; d4 < 16; ++d4) {
            float4 kv4 = kp[d4], qv4 = qp[d4];
            sim = fmaf(qv4.x, kv4.x, sim);
            sim = fmaf(qv4.y, kv4.y, sim);
            sim = fmaf(qv4.z, kv4.z, sim);
            sim = fmaf(qv4.w, kv4.w, sim);
        }
        // CPB bias MLP: 2 -> 64 -> 64 -> 1
        float px = gx - vg_s[j][0], py = gy - vg_s[j][1];
        float u = copysignf(log1pf(fabsf(px)), px);
        float vv = copysignf(log1pf(fabsf(py)), py);
        float h0[64];
        #pragma unroll
        for (int c = 0; c < 64; ++c)
            h0[c] = fmaxf(fmaf(w0[2 * c], u, fmaf(w0[2 * c + 1], vv, b0[c])), 0.f);
        float acc = b2[0];
        #pragma unroll 2
        for (int c2 = 0; c2 < 64; ++c2) {
            float hh = b1[c2];
            const float* wr = w1 + c2 * 64;
            #pragma unroll
            for (int d = 0; d < 64; ++d) hh = fmaf(wr[d], h0[d], hh);
            acc = fmaf(w2[c2], fmaxf(hh, 0.f), acc);
        }
        attn_s[il][j] = sim + acc;
    }
    __syncthreads();
    // row softmax (unnormalized exp; divide in out phase)
    {
        float m = -1e30f;
        for (int jj = 0; jj < 8; ++jj) m = fmaxf(m, attn_s[il][jj * 32 + lane]);
        #pragma unroll
        for (int o = 16; o > 0; o >>= 1) m = fmaxf(m, __shfl_xor(m, o, 32));
        float s = 0.f;
        for (int jj = 0; jj < 8; ++jj) {
            int j = jj * 32 + lane;
            float e = expf(attn_s[il][j] - m);
            attn_s[il][j] = e;
            s += e;
        }
        #pragma unroll
        for (int o = 16; o > 0; o >>= 1) s += __shfl_xor(s, o, 32);
        if (lane == 0) ssum_s[il] = s;
    }
    __syncthreads();
    // out[i][d] = (sum_j e_ij * v[j][d]) / ssum ; thread covers d = 2*lane, 2*lane+1
    {
        float a0 = 0.f, a1 = 0.f;
        const float2* vp = (const float2*)(vT + b * NQ * INNER + h * 64) + lane;
        for (int j = 0; j < NQ; ++j) {
            float a = attn_s[il][j];
            float2 vvv = vp[j * (INNER / 2)];
            a0 = fmaf(a, vvv.x, a0);
            a1 = fmaf(a, vvv.y, a1);
        }
        float r = 1.f / ssum_s[il];
        float* op = aoT + (b * NQ + iglob) * INNER + h * 64 + lane * 2;
        float2 res; res.x = a0 * r; res.y = a1 * r;
        *(float2*)op = res;
    }
}

// ---------------- K4: final projection 512 -> 256 ----------------
__global__ __launch_bounds__(256) void k4_proj(const float* __restrict__ aoT,
        const float* __restrict__ out_w, const float* __restrict__ out_b,
        float* __restrict__ out) {
    int b = blockIdx.x >> 6;
    int n0 = (blockIdx.x & 63) * 4;
    int t = threadIdx.x;
    __shared__ float xl[4][INNER];
    for (int idx = t; idx < 4 * INNER; idx += 256) {
        xl[idx >> 9][idx & 511] = aoT[(b * NQ + n0) * INNER + idx];
    }
    __syncthreads();
    float acc0, acc1, acc2, acc3;
    acc0 = acc1 = acc2 = acc3 = out_b[t];
    const float* w = out_w + t * INNER;
    for (int c = 0; c < INNER; ++c) {
        float wv = w[c];
        acc0 = fmaf(wv, xl[0][c], acc0);
        acc1 = fmaf(wv, xl[1][c], acc1);
        acc2 = fmaf(wv, xl[2][c], acc2);
        acc3 = fmaf(wv, xl[3][c], acc3);
    }
    float* op = out + (b * DIMC + t) * NQ + n0;
    op[0] = acc0; op[1] = acc1; op[2] = acc2; op[3] = acc3;
}

extern "C" void kernel_launch(void* const* d_in, const int* in_sizes, int n_in,
                              void* d_out, int out_size, void* d_ws, size_t ws_size,
                              hipStream_t stream) {
    const float* pose_feat = (const float*)d_in[0];
    const float* rgb       = (const float*)d_in[1];
    const float* pose_init = (const float*)d_in[2];
    const float* mha_in_w  = (const float*)d_in[3];
    const float* mha_in_b  = (const float*)d_in[4];
    const float* mha_out_w = (const float*)d_in[5];
    const float* mha_out_b = (const float*)d_in[6];
    const float* pe_gauss  = (const float*)d_in[7];
    const float* off_w1    = (const float*)d_in[8];
    const float* off_b1    = (const float*)d_in[9];
    const float* off_w2    = (const float*)d_in[10];
    const float* cpb_w0    = (const float*)d_in[11];
    const float* cpb_b0    = (const float*)d_in[12];
    const float* cpb_w1    = (const float*)d_in[13];
    const float* cpb_b1    = (const float*)d_in[14];
    const float* cpb_w2    = (const float*)d_in[15];
    const float* cpb_b2    = (const float*)d_in[16];
    const float* q_w       = (const float*)d_in[17];
    const float* k_w       = (const float*)d_in[18];
    const float* v_w       = (const float*)d_in[19];
    const float* out_w     = (const float*)d_in[20];
    const float* out_b     = (const float*)d_in[21];

    float* ws    = (float*)d_ws;
    float* kx    = ws;
    float* vx    = kx + 4 * 16 * 256;
    float* qT    = vx + 4 * 16 * 256;
    float* kT    = qT + 4 * 256 * 512;
    float* vT    = kT + 4 * 256 * 512;
    float* vgrid = vT + 4 * 256 * 512;
    float* aoT   = vgrid + 32 * 256 * 2;
    float* out   = (float*)d_out;

    k1_kv<<<64, 256, 0, stream>>>(rgb, mha_in_w, mha_in_b, kx, vx);
    k2_qkv<<<1024, 256, 0, stream>>>(pose_feat, rgb, pose_init, mha_in_w, mha_in_b,
        mha_out_w, mha_out_b, pe_gauss, off_w1, off_b1, off_w2, q_w, k_w, v_w,
        kx, vx, qT, kT, vT, vgrid);
    k3_attn<<<1024, 256, 0, stream>>>(pose_init, vgrid, qT, kT, vT,
        cpb_w0, cpb_b0, cpb_w1, cpb_b1, cpb_w2, cpb_b2, aoT);
    k4_proj<<<256, 256, 0, stream>>>(aoT, out_w, out_b, out);
}

// Round 2
// 308.573 us; speedup vs baseline: 3.1967x; 3.1967x over previous
//
#include <hip/hip_runtime.h>
#include <math.h>

// DeformableAttention2D — round 2: CPB bias MLP layer1 moved to bf16 MFMA.
// Sizes (fixed): B=4, N=256, DIM=256, HEADS=8, GROUPS=8, INNER=512, DH=64,
// cross-attn head dim 32, rgb 4x4 (16 tokens), CPB MLP 2->64->64->1.

#define DIMC 256
#define NQ 256
#define HEADS 8
#define GROUPS 8
#define INNER 512
#define DH 64      // deformable head dim
#define HDX 32     // cross-attn head dim
#define HWT 16     // rgb tokens (4*4)

typedef __attribute__((ext_vector_type(8))) short short8v;
typedef __attribute__((ext_vector_type(4))) float f32x4;
typedef unsigned short ushort_t;

__device__ __forceinline__ float gelu_exact(float x) {
    return 0.5f * x * (1.f + erff(x * 0.70710678118654752f));
}

__device__ __forceinline__ short f2bf(float x) {   // RNE f32 -> bf16 bits
    union { float f; unsigned u; } c; c.f = x;
    unsigned r = c.u + 0x7fffu + ((c.u >> 16) & 1u);
    return (short)(r >> 16);
}
__device__ __forceinline__ float bf2f(ushort_t h) {
    union { unsigned u; float f; } c; c.u = ((unsigned)h) << 16;
    return c.f;
}

__device__ __forceinline__ float samp4(const float* __restrict__ img, int yi, int xi) {
    bool valid = (xi >= 0) && (xi < 4) && (yi >= 0) && (yi < 4);
    int idx = min(max(yi, 0), 3) * 4 + min(max(xi, 0), 3);
    return valid ? img[idx] : 0.f;
}

// ---------------- K1: kx, vx  [b,16,256] ----------------
__global__ __launch_bounds__(256) void k1_kv(const float* __restrict__ rgb,
        const float* __restrict__ in_w, const float* __restrict__ in_b,
        float* __restrict__ kx, float* __restrict__ vx) {
    int b = blockIdx.x >> 4;
    int t = blockIdx.x & 15;
    int c = threadIdx.x;
    __shared__ float kvin[DIMC];
    float ang = (float)t * powf(10000.f, -(float)(c >> 1) * (1.f / 128.f));
    float sv = (c & 1) ? cosf(ang) : sinf(ang);
    kvin[c] = rgb[(b * DIMC + c) * HWT + t] + sv;
    __syncthreads();
    float ak = in_b[DIMC + c], av = in_b[2 * DIMC + c];
    const float* wk = in_w + (DIMC + c) * DIMC;
    const float* wv = in_w + (2 * DIMC + c) * DIMC;
    for (int d = 0; d < DIMC; ++d) {
        float x = kvin[d];
        ak = fmaf(wk[d], x, ak);
        av = fmaf(wv[d], x, av);
    }
    kx[(b * HWT + t) * DIMC + c] = ak;
    vx[(b * HWT + t) * DIMC + c] = av;
}

// ---------------- K2: per (b,n): cross-attn + q/offsets/sample + k/v ----------------
__global__ __launch_bounds__(256) void k2_qkv(
        const float* __restrict__ pose_feat, const float* __restrict__ rgb,
        const float* __restrict__ pose_init, const float* __restrict__ in_w,
        const float* __restrict__ in_b, const float* __restrict__ mow,
        const float* __restrict__ mob, const float* __restrict__ pe_gauss,
        const float* __restrict__ off_w1, const float* __restrict__ off_b1,
        const float* __restrict__ off_w2,
        const float* __restrict__ q_w, const float* __restrict__ k_w,
        const float* __restrict__ v_w,
        const float* __restrict__ kx, const float* __restrict__ vx,
        float* __restrict__ qT, float* __restrict__ kT, float* __restrict__ vT,
        float* __restrict__ vgrid_g) {
    int b = blockIdx.x >> 8, n = blockIdx.x & 255;
    int t = threadIdx.x;
    __shared__ float xs[DIMC], qxs[DIMC], lg[128], psm[128], ctx[DIMC], x2[DIMC];
    __shared__ float qls[INNER], kvs[DIMC];
    __shared__ float vgls[GROUPS][2];

    float p0 = pose_init[(b * 2 + 0) * NQ + n];
    float p1 = pose_init[(b * 2 + 1) * NQ + n];
    float g0 = 2.f * p0 - 1.f, g1 = 2.f * p1 - 1.f;

    float pfv = pose_feat[(b * DIMC + t) * NQ + n];
    {
        int j = t & 127;
        float cc = (g0 * pe_gauss[j] + g1 * pe_gauss[128 + j]) * 6.28318530717958648f;
        xs[t] = pfv + ((t < 128) ? sinf(cc) : cosf(cc));
    }
    __syncthreads();
    {
        float a = in_b[t];
        const float* w = in_w + t * DIMC;
        for (int d = 0; d < DIMC; ++d) a = fmaf(w[d], xs[d], a);
        qxs[t] = a;
    }
    __syncthreads();
    if (t < 128) {
        int h = t >> 4, tt = t & 15;
        const float* kp = kx + (b * HWT + tt) * DIMC + h * HDX;
        float a = 0.f;
        #pragma unroll
        for (int d = 0; d < HDX; ++d) a = fmaf(qxs[h * HDX + d], kp[d], a);
        lg[t] = a * 0.17677669529663689f;
    }
    __syncthreads();
    if (t < 8) {
        float m = -1e30f;
        for (int tt = 0; tt < 16; ++tt) m = fmaxf(m, lg[t * 16 + tt]);
        float s = 0.f;
        for (int tt = 0; tt < 16; ++tt) { float e = expf(lg[t * 16 + tt] - m); psm[t * 16 + tt] = e; s += e; }
        float r = 1.f / s;
        for (int tt = 0; tt < 16; ++tt) psm[t * 16 + tt] *= r;
    }
    __syncthreads();
    {
        int h = t >> 5;
        float a = 0.f;
        const float* vp = vx + b * HWT * DIMC + t;
        #pragma unroll
        for (int tt = 0; tt < 16; ++tt) a = fmaf(psm[h * 16 + tt], vp[tt * DIMC], a);
        ctx[t] = a;
    }
    __syncthreads();
    {
        float a = mob[t];
        const float* w = mow + t * DIMC;
        for (int d = 0; d < DIMC; ++d) a = fmaf(w[d], ctx[d], a);
        x2[t] = pfv + a;
    }
    __syncthreads();
    #pragma unroll
    for (int rep = 0; rep < 2; ++rep) {
        int ch = t + rep * 256;
        int g = ch >> 6;
        const float* w = q_w + ch * 32;
        const float* xp = x2 + g * 32;
        float a = 0.f;
        #pragma unroll
        for (int ci = 0; ci < 32; ++ci) a = fmaf(w[ci], xp[ci], a);
        qls[ch] = a;
        qT[(b * NQ + n) * INNER + ch] = a;
    }
    __syncthreads();
    {
        int g = t >> 5, l = t & 31;
        float s0 = 0.f, s1 = 0.f;
        #pragma unroll
        for (int jh = 0; jh < 2; ++jh) {
            int jj = l + 32 * jh;
            float e = gelu_exact(fmaf(qls[g * 64 + jj], off_w1[jj], off_b1[jj]));
            s0 = fmaf(e, off_w2[jj], s0);
            s1 = fmaf(e, off_w2[64 + jj], s1);
        }
        #pragma unroll
        for (int o = 16; o > 0; o >>= 1) {
            s0 += __shfl_xor(s0, o, 32);
            s1 += __shfl_xor(s1, o, 32);
        }
        if (l == 0) {
            float vgx = g0 + tanhf(s0) * (2.f / 3.f);
            float vgy = g1 + tanhf(s1) * (2.f / 3.f);
            vgls[g][0] = vgx; vgls[g][1] = vgy;
            float* vp = vgrid_g + ((b * GROUPS + g) * NQ + n) * 2;
            vp[0] = vgx; vp[1] = vgy;
        }
    }
    __syncthreads();
    {
        int g = t >> 5, c = t & 31;
        float x = (vgls[g][0] + 1.f) * 2.f - 0.5f;
        float y = (vgls[g][1] + 1.f) * 2.f - 0.5f;
        float x0f = floorf(x), y0f = floorf(y);
        float wx = x - x0f, wy = y - y0f;
        int x0 = (int)x0f, y0 = (int)y0f;
        const float* img = rgb + (b * DIMC + g * 32 + c) * HWT;
        float v00 = samp4(img, y0, x0), v01 = samp4(img, y0, x0 + 1);
        float v10 = samp4(img, y0 + 1, x0), v11 = samp4(img, y0 + 1, x0 + 1);
        kvs[t] = v00 * (1.f - wx) * (1.f - wy) + v01 * wx * (1.f - wy)
               + v10 * (1.f - wx) * wy + v11 * wx * wy;
    }
    __syncthreads();
    #pragma unroll
    for (int rep = 0; rep < 2; ++rep) {
        int ch = t + rep * 256;
        int g = ch >> 6;
        const float* xp = kvs + g * 32;
        const float* wkp = k_w + ch * 32;
        const float* wvp = v_w + ch * 32;
        float ak = 0.f, av = 0.f;
        #pragma unroll
        for (int ci = 0; ci < 32; ++ci) {
            float x = xp[ci];
            ak = fmaf(wkp[ci], x, ak);
            av = fmaf(wvp[ci], x, av);
        }
        kT[(b * NQ + n) * INNER + ch] = ak;
        vT[(b * NQ + n) * INNER + ch] = av;
    }
}

// ---------------- K3a: CPB bias via MFMA (layer1) ----------------
// grid: 32 bg * 16 jtiles; block 256 = 4 waves; wave handles 4 j, loops 16 i-tiles.
// A-frag (h0) computed per-lane; B-frag (w1) loaded per-lane with the SAME
// (lane,e)->k assignment, so the contraction is correct under any HW k-perm.
// Verified C/D map: col = lane&15 (c2/N), row = 4*(lane>>4)+reg (pair/M).
__global__ __launch_bounds__(256) void k3a_bias(
        const float* __restrict__ pose_init, const float* __restrict__ vgrid_g,
        const float* __restrict__ w0, const float* __restrict__ b0,
        const float* __restrict__ w1, const float* __restrict__ b1,
        const float* __restrict__ w2, const float* __restrict__ b2,
        ushort_t* __restrict__ bias) {
    int bg = blockIdx.x >> 4;      // 0..31
    int jt = blockIdx.x & 15;      // 0..15
    int b = bg >> 3;
    int tid = threadIdx.x;
    int wv = tid >> 6, lane = tid & 63;
    int lgp = lane >> 4, lr = lane & 15;

    __shared__ float gx_s[NQ], gy_s[NQ];
    gx_s[tid] = 2.f * pose_init[(b * 2 + 0) * NQ + tid] - 1.f;
    gy_s[tid] = 2.f * pose_init[(b * 2 + 1) * NQ + tid] - 1.f;
    __syncthreads();

    // per-lane weights
    float w0a[2][8], w0b[2][8], b0r[2][8];
    short8v bw1[2][4];
    float b1r[4], w2r[4];
    #pragma unroll
    for (int kc = 0; kc < 2; ++kc)
        #pragma unroll
        for (int e = 0; e < 8; ++e) {
            int c = kc * 32 + lgp * 8 + e;
            w0a[kc][e] = w0[2 * c];
            w0b[kc][e] = w0[2 * c + 1];
            b0r[kc][e] = b0[c];
        }
    #pragma unroll
    for (int nt = 0; nt < 4; ++nt) {
        int c2 = nt * 16 + lr;
        b1r[nt] = b1[c2];
        w2r[nt] = w2[c2];
        #pragma unroll
        for (int kc = 0; kc < 2; ++kc)
            #pragma unroll
            for (int e = 0; e < 8; ++e)
                bw1[kc][nt][e] = f2bf(w1[c2 * 64 + kc * 32 + lgp * 8 + e]);
    }
    float b2v = b2[0];

    int j0 = jt * 16 + wv * 4;
    const float* vgp = vgrid_g + bg * NQ * 2;
    #pragma unroll 1
    for (int it = 0; it < 16; ++it) {
        int i = it * 16 + lr;
        float gxi = gx_s[i], gyi = gy_s[i];
        #pragma unroll 1
        for (int jj = 0; jj < 4; ++jj) {
            int j = j0 + jj;
            float vgx = vgp[j * 2], vgy = vgp[j * 2 + 1];
            float px = gxi - vgx, py = gyi - vgy;
            float u = copysignf(__logf(1.f + fabsf(px)), px);
            float vvl = copysignf(__logf(1.f + fabsf(py)), py);
            short8v a0, a1;
            #pragma unroll
            for (int e = 0; e < 8; ++e) {
                float h = fmaf(w0a[0][e], u, fmaf(w0b[0][e], vvl, b0r[0][e]));
                a0[e] = f2bf(fmaxf(h, 0.f));
            }
            #pragma unroll
            for (int e = 0; e < 8; ++e) {
                float h = fmaf(w0a[1][e], u, fmaf(w0b[1][e], vvl, b0r[1][e]));
                a1[e] = f2bf(fmaxf(h, 0.f));
            }
            f32x4 acc0 = {0.f, 0.f, 0.f, 0.f};
            f32x4 acc1 = {0.f, 0.f, 0.f, 0.f};
            f32x4 acc2 = {0.f, 0.f, 0.f, 0.f};
            f32x4 acc3 = {0.f, 0.f, 0.f, 0.f};
            acc0 = __builtin_amdgcn_mfma_f32_16x16x32_bf16(a0, bw1[0][0], acc0, 0, 0, 0);
            acc0 = __builtin_amdgcn_mfma_f32_16x16x32_bf16(a1, bw1[1][0], acc0, 0, 0, 0);
            acc1 = __builtin_amdgcn_mfma_f32_16x16x32_bf16(a0, bw1[0][1], acc1, 0, 0, 0);
            acc1 = __builtin_amdgcn_mfma_f32_16x16x32_bf16(a1, bw1[1][1], acc1, 0, 0, 0);
            acc2 = __builtin_amdgcn_mfma_f32_16x16x32_bf16(a0, bw1[0][2], acc2, 0, 0, 0);
            acc2 = __builtin_amdgcn_mfma_f32_16x16x32_bf16(a1, bw1[1][2], acc2, 0, 0, 0);
            acc3 = __builtin_amdgcn_mfma_f32_16x16x32_bf16(a0, bw1[0][3], acc3, 0, 0, 0);
            acc3 = __builtin_amdgcn_mfma_f32_16x16x32_bf16(a1, bw1[1][3], acc3, 0, 0, 0);
            #pragma unroll
            for (int r = 0; r < 4; ++r) {
                float s = fmaxf(acc0[r] + b1r[0], 0.f) * w2r[0]
                        + fmaxf(acc1[r] + b1r[1], 0.f) * w2r[1]
                        + fmaxf(acc2[r] + b1r[2], 0.f) * w2r[2]
                        + fmaxf(acc3[r] + b1r[3], 0.f) * w2r[3];
                s += __shfl_xor(s, 1, 64);
                s += __shfl_xor(s, 2, 64);
                s += __shfl_xor(s, 4, 64);
                s += __shfl_xor(s, 8, 64);
                if (lr == 0)
                    bias[(bg * NQ + it * 16 + lgp * 4 + r) * NQ + j] = (ushort_t)f2bf(s + b2v);
            }
        }
    }
}

// ---------------- K3b: sim + bias + softmax + attn@V ----------------
__global__ __launch_bounds__(256) void k3b_attn(
        const float* __restrict__ qT, const float* __restrict__ kT,
        const float* __restrict__ vT, const ushort_t* __restrict__ bias,
        float* __restrict__ aoT) {
    int bg = blockIdx.x >> 5;        // 0..31
    int itile = blockIdx.x & 31;     // 0..31
    int b = bg >> 3, h = bg & 7;
    int i0 = itile * 8;
    int tid = threadIdx.x;
    int il = tid >> 5, lane = tid & 31;

    __shared__ __align__(16) float q_s[8][64];
    __shared__ float attn_s[8][NQ];
    __shared__ float ssum_s[8];

    for (int idx = tid; idx < 8 * 64; idx += 256) {
        int i = idx >> 6, d = idx & 63;
        q_s[i][d] = qT[(b * NQ + i0 + i) * INNER + h * 64 + d] * 0.125f;
    }
    __syncthreads();

    const int iglob = i0 + il;
    const ushort_t* brow = bias + (bg * NQ + iglob) * NQ;

    #pragma unroll 1
    for (int jj = 0; jj < 8; ++jj) {
        int j = jj * 32 + lane;
        float sim = 0.f;
        const float4* kp = (const float4*)(kT + (b * NQ + j) * INNER + h * 64);
        const float4* qp = (const float4*)(&q_s[il][0]);
        #pragma unroll
        for (int d4 = 0; d4 < 16; ++d4) {
            float4 kv4 = kp[d4], qv4 = qp[d4];
            sim = fmaf(qv4.x, kv4.x, sim);
            sim = fmaf(qv4.y, kv4.y, sim);
            sim = fmaf(qv4.z, kv4.z, sim);
            sim = fmaf(qv4.w, kv4.w, sim);
        }
        attn_s[il][j] = sim + bf2f(brow[j]);
    }
    __syncthreads();
    {
        float m = -1e30f;
        for (int jj = 0; jj < 8; ++jj) m = fmaxf(m, attn_s[il][jj * 32 + lane]);
        #pragma unroll
        for (int o = 16; o > 0; o >>= 1) m = fmaxf(m, __shfl_xor(m, o, 32));
        float s = 0.f;
        for (int jj = 0; jj < 8; ++jj) {
            int j = jj * 32 + lane;
            float e = __expf(attn_s[il][j] - m);
            attn_s[il][j] = e;
            s += e;
        }
        #pragma unroll
        for (int o = 16; o > 0; o >>= 1) s += __shfl_xor(s, o, 32);
        if (lane == 0) ssum_s[il] = s;
    }
    __syncthreads();
    {
        float a0 = 0.f, a1 = 0.f;
        const float2* vp = (const float2*)(vT + b * NQ * INNER + h * 64) + lane;
        for (int j = 0; j < NQ; ++j) {
            float a = attn_s[il][j];
            float2 vvv = vp[j * (INNER / 2)];
            a0 = fmaf(a, vvv.x, a0);
            a1 = fmaf(a, vvv.y, a1);
        }
        float r = 1.f / ssum_s[il];
        float* op = aoT + (b * NQ + iglob) * INNER + h * 64 + lane * 2;
        float2 res; res.x = a0 * r; res.y = a1 * r;
        *(float2*)op = res;
    }
}

// ---------------- K4: final projection 512 -> 256 ----------------
__global__ __launch_bounds__(256) void k4_proj(const float* __restrict__ aoT,
        const float* __restrict__ out_w, const float* __restrict__ out_b,
        float* __restrict__ out) {
    int b = blockIdx.x >> 6;
    int n0 = (blockIdx.x & 63) * 4;
    int t = threadIdx.x;
    __shared__ float xl[4][INNER];
    for (int idx = t; idx < 4 * INNER; idx += 256) {
        xl[idx >> 9][idx & 511] = aoT[(b * NQ + n0) * INNER + idx];
    }
    __syncthreads();
    float acc0, acc1, acc2, acc3;
    acc0 = acc1 = acc2 = acc3 = out_b[t];
    const float* w = out_w + t * INNER;
    for (int c = 0; c < INNER; ++c) {
        float wv = w[c];
        acc0 = fmaf(wv, xl[0][c], acc0);
        acc1 = fmaf(wv, xl[1][c], acc1);
        acc2 = fmaf(wv, xl[2][c], acc2);
        acc3 = fmaf(wv, xl[3][c], acc3);
    }
    float* op = out + (b * DIMC + t) * NQ + n0;
    op[0] = acc0; op[1] = acc1; op[2] = acc2; op[3] = acc3;
}

extern "C" void kernel_launch(void* const* d_in, const int* in_sizes, int n_in,
                              void* d_out, int out_size, void* d_ws, size_t ws_size,
                              hipStream_t stream) {
    const float* pose_feat = (const float*)d_in[0];
    const float* rgb       = (const float*)d_in[1];
    const float* pose_init = (const float*)d_in[2];
    const float* mha_in_w  = (const float*)d_in[3];
    const float* mha_in_b  = (const float*)d_in[4];
    const float* mha_out_w = (const float*)d_in[5];
    const float* mha_out_b = (const float*)d_in[6];
    const float* pe_gauss  = (const float*)d_in[7];
    const float* off_w1    = (const float*)d_in[8];
    const float* off_b1    = (const float*)d_in[9];
    const float* off_w2    = (const float*)d_in[10];
    const float* cpb_w0    = (const float*)d_in[11];
    const float* cpb_b0    = (const float*)d_in[12];
    const float* cpb_w1    = (const float*)d_in[13];
    const float* cpb_b1    = (const float*)d_in[14];
    const float* cpb_w2    = (const float*)d_in[15];
    const float* cpb_b2    = (const float*)d_in[16];
    const float* q_w       = (const float*)d_in[17];
    const float* k_w       = (const float*)d_in[18];
    const float* v_w       = (const float*)d_in[19];
    const float* out_w     = (const float*)d_in[20];
    const float* out_b     = (const float*)d_in[21];

    float* ws    = (float*)d_ws;
    float* kx    = ws;
    float* vx    = kx + 4 * 16 * 256;
    float* qT    = vx + 4 * 16 * 256;
    float* kT    = qT + 4 * 256 * 512;
    float* vT    = kT + 4 * 256 * 512;
    float* vgrid = vT + 4 * 256 * 512;
    float* aoT   = vgrid + 32 * 256 * 2;
    ushort_t* bias = (ushort_t*)(aoT + 4 * 256 * 512);   // 32*256*256 bf16 = 4 MB
    float* out   = (float*)d_out;

    k1_kv<<<64, 256, 0, stream>>>(rgb, mha_in_w, mha_in_b, kx, vx);
    k2_qkv<<<1024, 256, 0, stream>>>(pose_feat, rgb, pose_init, mha_in_w, mha_in_b,
        mha_out_w, mha_out_b, pe_gauss, off_w1, off_b1, off_w2, q_w, k_w, v_w,
        kx, vx, qT, kT, vT, vgrid);
    k3a_bias<<<512, 256, 0, stream>>>(pose_init, vgrid,
        cpb_w0, cpb_b0, cpb_w1, cpb_b1, cpb_w2, cpb_b2, bias);
    k3b_attn<<<1024, 256, 0, stream>>>(qT, kT, vT, bias, aoT);
    k4_proj<<<256, 256, 0, stream>>>(aoT, out_w, out_b, out);
}